// Round 3
// baseline (2976.587 us; speedup 1.0000x reference)
//
#include <hip/hip_runtime.h>
#include <stdint.h>

#define D 128
#define B 2048
#define N 100000
#define K 50

#define NCHUNK 16
#define CN 6400           // keys per chunk
#define BQ 128            // queries per block (phase 1)
#define BN 128            // keys per subtile
#define QSTR 132          // sQ row stride (floats): 4 mod 32 -> 2-way (free), 16B aligned
#define KSTR 36           // sK row stride (floats)
#define DSTR 129          // sD row stride (floats)
#define KCH 64            // kept per chunk (full wave)
#define CPQ (NCHUNK * KCH)   // 1024 candidates per query

// opaque: blocks fp-contract across this value (forces numpy-style per-op rounding)
__device__ __forceinline__ float opq(float x) { asm volatile("" : "+v"(x)); return x; }

// ---------------- Phase 0: row norms (feeds fp32 filter only) ----------------
__global__ void k_norms(const float* __restrict__ q, const float* __restrict__ k,
                        float* __restrict__ qn, float* __restrict__ kn) {
    int wid = threadIdx.x >> 6, lane = threadIdx.x & 63;
    int row = blockIdx.x * 4 + wid;
    const float* src;
    float* dst;
    if (row < N) {
        src = k + (size_t)row * D; dst = kn + row;
    } else {
        int r = row - N;
        if (r >= B) return;
        src = q + (size_t)r * D; dst = qn + r;
    }
    float2 v = ((const float2*)src)[lane];
    float s = v.x * v.x + v.y * v.y;
    #pragma unroll
    for (int o = 32; o; o >>= 1) s += __shfl_down(s, o);
    if (lane == 0) *dst = s;
}

// ---------------- Phase 1: fp32 distance GEMM + per-chunk top-64 filter ----------------
__launch_bounds__(256, 1)
__global__ void k_phase1(const float* __restrict__ Q, const float* __restrict__ Ky,
                         const float* __restrict__ qn, const float* __restrict__ kn,
                         unsigned long long* __restrict__ cand) {
    __shared__ __align__(16) float sQ[BQ * QSTR];
    __shared__ __align__(16) float sK[BN * KSTR];
    __shared__ __align__(16) float sD[BQ * DSTR];

    const int tid = threadIdx.x;
    const int tx = tid & 15, ty = tid >> 4;
    const int wv = tid >> 6, lane = tid & 63;
    const int chunk = blockIdx.x, qtile = blockIdx.y;
    const int kbase = chunk * CN;
    const int qbase = qtile * BQ;

    {
        int r = tid >> 1, half = tid & 1;
        const float4* src = (const float4*)(Q + (size_t)(qbase + r) * D + half * 64);
        #pragma unroll
        for (int i = 0; i < 16; ++i) {
            float4 vv = src[i];
            *((float4*)&sQ[r * QSTR + half * 64 + i * 4]) = vv;
        }
    }
    float qnr[8];
    #pragma unroll
    for (int a = 0; a < 8; ++a) qnr[a] = qn[qbase + ty + 16 * a];

    // per-row top-64, lane-distributed sorted ascending
    unsigned long long v[32];
    #pragma unroll
    for (int r = 0; r < 32; ++r) v[r] = ~0ULL;

    int rem = N - kbase;
    int nst = (rem >= CN) ? (CN / BN) : ((rem + BN - 1) / BN);

    for (int st = 0; st < nst; ++st) {
        int sbase = kbase + st * BN;
        float acc[8][8];
        #pragma unroll
        for (int a = 0; a < 8; ++a)
            #pragma unroll
            for (int b = 0; b < 8; ++b) acc[a][b] = 0.0f;

        for (int ds = 0; ds < 4; ++ds) {
            __syncthreads();
            {
                int rr = tid >> 3;
                int dd = (tid & 7) * 4;
                #pragma unroll
                for (int m = 0; m < 4; ++m) {
                    int row = rr + 32 * m;
                    int g = sbase + row;
                    int gg = (g < N) ? g : (N - 1);
                    float4 val = *(const float4*)(Ky + (size_t)gg * D + ds * 32 + dd);
                    *(float4*)&sK[row * KSTR + dd] = val;
                }
            }
            __syncthreads();
            #pragma unroll
            for (int d4 = 0; d4 < 8; ++d4) {
                float4 qv[8], kv[8];
                #pragma unroll
                for (int a = 0; a < 8; ++a)
                    qv[a] = *(const float4*)&sQ[(ty + 16 * a) * QSTR + ds * 32 + d4 * 4];
                #pragma unroll
                for (int b = 0; b < 8; ++b)
                    kv[b] = *(const float4*)&sK[(tx + 16 * b) * KSTR + d4 * 4];
                #pragma unroll
                for (int a = 0; a < 8; ++a) {
                    #pragma unroll
                    for (int b = 0; b < 8; ++b) {
                        acc[a][b] = __builtin_fmaf(qv[a].x, kv[b].x, acc[a][b]);
                        acc[a][b] = __builtin_fmaf(qv[a].y, kv[b].y, acc[a][b]);
                        acc[a][b] = __builtin_fmaf(qv[a].z, kv[b].z, acc[a][b]);
                        acc[a][b] = __builtin_fmaf(qv[a].w, kv[b].w, acc[a][b]);
                    }
                }
            }
        }
        __syncthreads();
        #pragma unroll
        for (int b = 0; b < 8; ++b) {
            int g = sbase + tx + 16 * b;
            float knb = (g < N) ? kn[g] : __builtin_inff();
            #pragma unroll
            for (int a = 0; a < 8; ++a) {
                float dist = fmaxf(qnr[a] + knb - 2.0f * acc[a][b], 0.0f);
                sD[(ty + 16 * a) * DSTR + tx + 16 * b] = dist;
            }
        }
        __syncthreads();
        #pragma unroll
        for (int r = 0; r < 32; ++r) {
            int ql = 32 * wv + r;
            unsigned long long mx = __shfl(v[r], 63);
            #pragma unroll
            for (int half = 0; half < 2; ++half) {
                int col = lane + 64 * half;
                float dd = sD[ql * DSTR + col];
                unsigned long long c =
                    ((unsigned long long)__float_as_uint(dd) << 32) | (unsigned)(sbase + col);
                unsigned long long qual = __ballot(c < mx);
                while (qual) {
                    int s = __ffsll((long long)qual) - 1;
                    unsigned long long cv = __shfl(c, s);
                    qual &= qual - 1;
                    unsigned long long gt = __ballot(v[r] > cv);
                    int p = __ffsll((long long)gt) - 1;
                    unsigned long long sh = __shfl_up(v[r], 1);
                    v[r] = (lane < p) ? v[r] : ((lane == p) ? cv : sh);
                    mx = __shfl(v[r], 63);
                    qual &= __ballot(c < mx);
                }
            }
        }
    }
    #pragma unroll
    for (int r = 0; r < 32; ++r) {
        int q = qbase + 32 * wv + r;
        cand[(size_t)q * CPQ + chunk * KCH + lane] = v[r];
    }
}

// ---------------- Phase 2: numpy-faithful fp32 rescore of 1024 candidates ----------------
__global__ void k_phase2(const float* __restrict__ Q, const float* __restrict__ Ky,
                         const float* __restrict__ V,
                         const unsigned long long* __restrict__ cand,
                         float* __restrict__ out) {
    __shared__ unsigned long long s[CPQ];
    __shared__ __align__(16) float qs[D];
    __shared__ float sww[64], svv[64];
    int t = threadIdx.x, q = blockIdx.x;

    if (t < D) qs[t] = Q[(size_t)q * D + t];
    __syncthreads();

    // qn: numpy pairwise n=128 (8 accumulators, per-element rounded squares)
    float qn;
    {
        const float4* qr = (const float4*)qs;
        float r[8];
        #pragma unroll
        for (int c4 = 0; c4 < 32; ++c4) {
            float4 v4 = qr[c4];
            int j = (c4 & 1) * 4;
            float p0 = opq(v4.x * v4.x), p1 = opq(v4.y * v4.y);
            float p2 = opq(v4.z * v4.z), p3 = opq(v4.w * v4.w);
            if (c4 < 2) { r[j] = p0; r[j + 1] = p1; r[j + 2] = p2; r[j + 3] = p3; }
            else        { r[j] += p0; r[j + 1] += p1; r[j + 2] += p2; r[j + 3] += p3; }
        }
        qn = ((r[0] + r[1]) + (r[2] + r[3])) + ((r[4] + r[5]) + (r[6] + r[7]));
    }

    // score all 1024 candidates with numpy-emulated expansion-form distance
    #pragma unroll
    for (int m = 0; m < 4; ++m) {
        int i = t + 256 * m;
        unsigned nb = (unsigned)(cand[(size_t)q * CPQ + i] & 0xffffffffu);
        unsigned long long pk;
        if (nb < N) {
            const float4* kr = (const float4*)(Ky + (size_t)nb * D);
            const float4* qr = (const float4*)qs;
            float acc = 0.0f;     // sgemm: single-accumulator sequential FMA over k
            float r[8];           // kn: numpy pairwise n=128
            #pragma unroll
            for (int c4 = 0; c4 < 32; ++c4) {
                float4 kv = kr[c4];
                float4 qv = qr[c4];
                acc = __builtin_fmaf(qv.x, kv.x, acc);
                acc = __builtin_fmaf(qv.y, kv.y, acc);
                acc = __builtin_fmaf(qv.z, kv.z, acc);
                acc = __builtin_fmaf(qv.w, kv.w, acc);
                int j = (c4 & 1) * 4;
                float p0 = opq(kv.x * kv.x), p1 = opq(kv.y * kv.y);
                float p2 = opq(kv.z * kv.z), p3 = opq(kv.w * kv.w);
                if (c4 < 2) { r[j] = p0; r[j + 1] = p1; r[j + 2] = p2; r[j + 3] = p3; }
                else        { r[j] += p0; r[j + 1] += p1; r[j + 2] += p2; r[j + 3] += p3; }
            }
            float kn = ((r[0] + r[1]) + (r[2] + r[3])) + ((r[4] + r[5]) + (r[6] + r[7]));
            float t1 = opq(2.0f * acc);   // exact; barrier blocks fma-contraction
            float t2 = opq(qn - t1);      // numpy: (qn - 2ab) rounds
            float dnp = t2 + kn;          // then + kn rounds
            pk = ((unsigned long long)__float_as_uint(dnp) << 32) | nb;
        } else {
            pk = ~0ULL;
        }
        s[i] = pk;
    }
    __syncthreads();

    // bitonic sort 1024 u64 ascending => numpy top_k(-d) with lowest-index ties
    for (int k2 = 2; k2 <= CPQ; k2 <<= 1) {
        for (int j = k2 >> 1; j > 0; j >>= 1) {
            #pragma unroll
            for (int m = 0; m < 4; ++m) {
                int i = t + 256 * m;
                int ixj = i ^ j;
                if (ixj > i) {
                    bool up = ((i & k2) == 0);
                    unsigned long long a = s[i], b = s[ixj];
                    if ((a > b) == up) { s[i] = b; s[ixj] = a; }
                }
            }
            __syncthreads();
        }
    }

    // numpy-faithful direct-form rescore of top-50 + weights
    if (t < 64) { sww[t] = 0.0f; svv[t] = 0.0f; }
    __syncthreads();
    if (t < K) {
        unsigned nb = (unsigned)(s[t] & 0xffffffffu);
        const float4* kr = (const float4*)(Ky + (size_t)nb * D);
        const float4* qr = (const float4*)qs;
        float r[8];
        #pragma unroll
        for (int c4 = 0; c4 < 32; ++c4) {
            float4 kv = kr[c4];
            float4 qv = qr[c4];
            float d0 = qv.x - kv.x, d1 = qv.y - kv.y;
            float d2 = qv.z - kv.z, d3 = qv.w - kv.w;
            float p0 = opq(d0 * d0), p1 = opq(d1 * d1);
            float p2 = opq(d2 * d2), p3 = opq(d3 * d3);
            int j = (c4 & 1) * 4;
            if (c4 < 2) { r[j] = p0; r[j + 1] = p1; r[j + 2] = p2; r[j + 3] = p3; }
            else        { r[j] += p0; r[j + 1] += p1; r[j + 2] += p2; r[j + 3] += p3; }
        }
        float sq = ((r[0] + r[1]) + (r[2] + r[3])) + ((r[4] + r[5]) + (r[6] + r[7]));
        sww[t] = 1.0f / (sq + 1e-3f);
        svv[t] = V[nb];
    }
    __syncthreads();
    if (t == 0) {
        // W = numpy pairwise sum n=50: 8 accs over 48, remainder 2
        float r[8];
        #pragma unroll
        for (int j = 0; j < 8; ++j) r[j] = sww[j];
        for (int i = 8; i < 48; i += 8)
            #pragma unroll
            for (int j = 0; j < 8; ++j) r[j] += sww[i + j];
        float W = ((r[0] + r[1]) + (r[2] + r[3])) + ((r[4] + r[5]) + (r[6] + r[7]));
        W += sww[48];
        W += sww[49];
        // out = numpy pairwise sum n=50 of (w/W)*v, per-element rounded
        float p[50];
        for (int i = 0; i < 50; ++i) {
            float wn = opq(sww[i] / W);
            p[i] = opq(wn * svv[i]);
        }
        #pragma unroll
        for (int j = 0; j < 8; ++j) r[j] = p[j];
        for (int i = 8; i < 48; i += 8)
            #pragma unroll
            for (int j = 0; j < 8; ++j) r[j] += p[i + j];
        float res = ((r[0] + r[1]) + (r[2] + r[3])) + ((r[4] + r[5]) + (r[6] + r[7]));
        res += p[48];
        res += p[49];
        out[q] = res;
    }
}

extern "C" void kernel_launch(void* const* d_in, const int* in_sizes, int n_in,
                              void* d_out, int out_size, void* d_ws, size_t ws_size,
                              hipStream_t stream) {
    const float* Q  = (const float*)d_in[0];
    const float* Ky = (const float*)d_in[1];
    const float* V  = (const float*)d_in[2];
    float* out = (float*)d_out;

    float* kn = (float*)d_ws;                 // 100000 floats
    float* qn = kn + N;                       // 2048 floats
    unsigned long long* cand = (unsigned long long*)(qn + B);  // 2048*1024 u64

    k_norms<<<dim3((N + B) / 4), 256, 0, stream>>>(Q, Ky, qn, kn);
    k_phase1<<<dim3(NCHUNK, B / BQ), 256, 0, stream>>>(Q, Ky, qn, kn, cand);
    k_phase2<<<dim3(B), 256, 0, stream>>>(Q, Ky, V, cand, out);
}

// Round 4
// 1184.509 us; speedup vs baseline: 2.5129x; 2.5129x over previous
//
#include <hip/hip_runtime.h>
#include <stdint.h>

#define D 128
#define B 2048
#define N 100000
#define K 50

#define NCHUNK 8
#define CN 12544          // keys per chunk (98 subtiles of 128)
#define BQ 64             // queries per block (phase 1)
#define BN 128            // keys per subtile
#define KCH 64            // kept per chunk (full wave)
#define CPQ (NCHUNK * KCH)   // 512 candidates per query
#define DSTR 128

typedef unsigned long long u64;
typedef __attribute__((ext_vector_type(8))) __bf16 bf16x8;
typedef __attribute__((ext_vector_type(4))) float f32x4;

// opaque: blocks fp-contract across this value (forces numpy-style per-op rounding)
__device__ __forceinline__ float opq(float x) { asm volatile("" : "+v"(x)); return x; }

// manual RNE f32 -> bf16 bits
__device__ __forceinline__ unsigned f2bf(float x) {
    unsigned u = __float_as_uint(x);
    u += 0x7fffu + ((u >> 16) & 1u);
    return u >> 16;
}

// ---------------- Phase 0: row norms (feeds fp32 filter only) ----------------
__global__ void k_norms(const float* __restrict__ q, const float* __restrict__ k,
                        float* __restrict__ qn, float* __restrict__ kn) {
    int wid = threadIdx.x >> 6, lane = threadIdx.x & 63;
    int row = blockIdx.x * 4 + wid;
    const float* src;
    float* dst;
    if (row < N) {
        src = k + (size_t)row * D; dst = kn + row;
    } else {
        int r = row - N;
        if (r >= B) return;
        src = q + (size_t)r * D; dst = qn + r;
    }
    float2 v = ((const float2*)src)[lane];
    float s = v.x * v.x + v.y * v.y;
    #pragma unroll
    for (int o = 32; o; o >>= 1) s += __shfl_down(s, o);
    if (lane == 0) *dst = s;
}

// ---------------- Phase 1: bf16 MFMA filter GEMM + per-chunk top-64 ----------------
// XOR-granule swizzle: 16B granule g of row r stored at g ^ (r & 15) -> conflict-free
// MFMA fragment reads without padding (row stride 256 B).
__launch_bounds__(512, 2)
__global__ void k_phase1(const float* __restrict__ Q, const float* __restrict__ Ky,
                         const float* __restrict__ qn, const float* __restrict__ kn,
                         u64* __restrict__ cand) {
    __shared__ __align__(16) unsigned short sQ[BQ * 128];   // 16 KB bf16, swizzled
    __shared__ __align__(16) unsigned short sK[BN * 128];   // 32 KB bf16, swizzled
    __shared__ __align__(16) float sD[BQ * DSTR];           // 32 KB distances

    const int tid = threadIdx.x;
    const int wv = tid >> 6, lane = tid & 63;
    const int chunk = blockIdx.x, qtile = blockIdx.y;
    const int kbase = chunk * CN;
    const int qbase = qtile * BQ;
    const int mt = wv >> 1;          // m-tile (16 rows) this wave computes
    const int nh = wv & 1;           // n-half (64 cols)

    // stage sQ (convert to bf16, swizzled): thread t -> row t>>3, floats (t&7)*16
    {
        int r = tid >> 3, c0 = (tid & 7) * 16;
        const float4* src = (const float4*)(Q + (size_t)(qbase + r) * D + c0);
        float4 f0 = src[0], f1 = src[1], f2 = src[2], f3 = src[3];
        int g0 = ((tid & 7) * 2) ^ (r & 15);
        int g1 = ((tid & 7) * 2 + 1) ^ (r & 15);
        uint4 pa, pb;
        pa.x = f2bf(f0.x) | (f2bf(f0.y) << 16);
        pa.y = f2bf(f0.z) | (f2bf(f0.w) << 16);
        pa.z = f2bf(f1.x) | (f2bf(f1.y) << 16);
        pa.w = f2bf(f1.z) | (f2bf(f1.w) << 16);
        pb.x = f2bf(f2.x) | (f2bf(f2.y) << 16);
        pb.y = f2bf(f2.z) | (f2bf(f2.w) << 16);
        pb.z = f2bf(f3.x) | (f2bf(f3.y) << 16);
        pb.w = f2bf(f3.z) | (f2bf(f3.w) << 16);
        *(uint4*)&sQ[r * 128 + g0 * 8] = pa;
        *(uint4*)&sQ[r * 128 + g1 * 8] = pb;
    }

    // per-thread query norms (C-layout rows: mt*16 + (lane>>4)*4 + j)
    float qnr[4];
    #pragma unroll
    for (int j = 0; j < 4; ++j)
        qnr[j] = qn[qbase + mt * 16 + (lane >> 4) * 4 + j];

    // per-row top-64, lane-distributed sorted ascending (wave owns rows 8*wv..+7)
    u64 v[8];
    #pragma unroll
    for (int r = 0; r < 8; ++r) v[r] = ~0ULL;

    int rem = N - kbase;
    int nst = (rem + BN - 1) >> 7;
    if (nst > CN / BN) nst = CN / BN;

    for (int st = 0; st < nst; ++st) {
        int sbase = kbase + st * BN;
        // stage sK (convert to bf16, swizzled): thread t -> row t>>2, floats (t&3)*32
        {
            int r = tid >> 2, c0 = (tid & 3) * 32;
            int grow = sbase + r;
            int gg = (grow < N) ? grow : (N - 1);
            const float4* src = (const float4*)(Ky + (size_t)gg * D + c0);
            #pragma unroll
            for (int h = 0; h < 4; ++h) {
                float4 fa = src[2 * h], fb = src[2 * h + 1];
                int g = ((tid & 3) * 4 + h) ^ (r & 15);
                uint4 p;
                p.x = f2bf(fa.x) | (f2bf(fa.y) << 16);
                p.y = f2bf(fa.z) | (f2bf(fa.w) << 16);
                p.z = f2bf(fb.x) | (f2bf(fb.y) << 16);
                p.w = f2bf(fb.z) | (f2bf(fb.w) << 16);
                *(uint4*)&sK[r * 128 + g * 8] = p;
            }
        }
        __syncthreads();

        // MFMA: wave computes 16q x 64k, K=128 in 4 steps of 32
        f32x4 acc[4];
        #pragma unroll
        for (int n = 0; n < 4; ++n) acc[n] = (f32x4){0.f, 0.f, 0.f, 0.f};
        int mrow = mt * 16 + (lane & 15);
        #pragma unroll
        for (int ks = 0; ks < 4; ++ks) {
            int g = (ks * 4 + (lane >> 4)) ^ (lane & 15);   // row&15 == lane&15
            bf16x8 a = *(const bf16x8*)&sQ[mrow * 128 + g * 8];
            #pragma unroll
            for (int n = 0; n < 4; ++n) {
                int nrow = (nh * 4 + n) * 16 + (lane & 15);
                bf16x8 b = *(const bf16x8*)&sK[nrow * 128 + g * 8];
                acc[n] = __builtin_amdgcn_mfma_f32_16x16x32_bf16(a, b, acc[n], 0, 0, 0);
            }
        }

        // epilogue: d = qn + kn - 2*S  (filter metric), write to sD
        #pragma unroll
        for (int n = 0; n < 4; ++n) {
            int col = (nh * 4 + n) * 16 + (lane & 15);
            int gcol = sbase + col;
            float knv = (gcol < N) ? kn[gcol] : __builtin_inff();
            #pragma unroll
            for (int j = 0; j < 4; ++j) {
                int row = mt * 16 + (lane >> 4) * 4 + j;
                float dist = fmaxf(__builtin_fmaf(-2.0f, acc[n][j], qnr[j] + knv), 0.0f);
                sD[row * DSTR + col] = dist;
            }
        }
        __syncthreads();

        // selection: wave wv owns rows 8*wv .. 8*wv+7
        #pragma unroll
        for (int r = 0; r < 8; ++r) {
            int ql = 8 * wv + r;
            u64 mx = __shfl(v[r], 63);
            #pragma unroll
            for (int half = 0; half < 2; ++half) {
                int col = lane + 64 * half;
                float dd = sD[ql * DSTR + col];
                u64 c = ((u64)__float_as_uint(dd) << 32) | (unsigned)(sbase + col);
                u64 qual = __ballot(c < mx);
                while (qual) {
                    int s = __ffsll((long long)qual) - 1;
                    u64 cv = __shfl(c, s);
                    qual &= qual - 1;
                    u64 gt = __ballot(v[r] > cv);
                    int p = __ffsll((long long)gt) - 1;
                    u64 sh = __shfl_up(v[r], 1);
                    v[r] = (lane < p) ? v[r] : ((lane == p) ? cv : sh);
                    mx = __shfl(v[r], 63);
                    qual &= __ballot(c < mx);
                }
            }
        }
        __syncthreads();
    }
    #pragma unroll
    for (int r = 0; r < 8; ++r) {
        int q = qbase + 8 * wv + r;
        cand[(size_t)q * CPQ + chunk * KCH + lane] = v[r];
    }
}

// ---------------- Phase 2: numpy-faithful fp32 rescore of 512 candidates ----------------
__global__ void k_phase2(const float* __restrict__ Q, const float* __restrict__ Ky,
                         const float* __restrict__ V,
                         const u64* __restrict__ cand,
                         float* __restrict__ out) {
    __shared__ u64 s[CPQ];
    __shared__ __align__(16) float qs[D];
    __shared__ float sww[64], svv[64];
    int t = threadIdx.x, q = blockIdx.x;

    if (t < D) qs[t] = Q[(size_t)q * D + t];
    __syncthreads();

    // qn: numpy pairwise n=128 (8 accumulators, per-element rounded squares)
    float qn;
    {
        const float4* qr = (const float4*)qs;
        float r[8];
        #pragma unroll
        for (int c4 = 0; c4 < 32; ++c4) {
            float4 v4 = qr[c4];
            int j = (c4 & 1) * 4;
            float p0 = opq(v4.x * v4.x), p1 = opq(v4.y * v4.y);
            float p2 = opq(v4.z * v4.z), p3 = opq(v4.w * v4.w);
            if (c4 < 2) { r[j] = p0; r[j + 1] = p1; r[j + 2] = p2; r[j + 3] = p3; }
            else        { r[j] += p0; r[j + 1] += p1; r[j + 2] += p2; r[j + 3] += p3; }
        }
        qn = ((r[0] + r[1]) + (r[2] + r[3])) + ((r[4] + r[5]) + (r[6] + r[7]));
    }

    // score all 512 candidates with numpy-emulated expansion-form distance
    #pragma unroll
    for (int m = 0; m < 2; ++m) {
        int i = t + 256 * m;
        unsigned nb = (unsigned)(cand[(size_t)q * CPQ + i] & 0xffffffffu);
        u64 pk;
        if (nb < N) {
            const float4* kr = (const float4*)(Ky + (size_t)nb * D);
            const float4* qr = (const float4*)qs;
            float acc = 0.0f;     // sgemm: single-accumulator sequential FMA over k
            float r[8];           // kn: numpy pairwise n=128
            #pragma unroll
            for (int c4 = 0; c4 < 32; ++c4) {
                float4 kv = kr[c4];
                float4 qv = qr[c4];
                acc = __builtin_fmaf(qv.x, kv.x, acc);
                acc = __builtin_fmaf(qv.y, kv.y, acc);
                acc = __builtin_fmaf(qv.z, kv.z, acc);
                acc = __builtin_fmaf(qv.w, kv.w, acc);
                int j = (c4 & 1) * 4;
                float p0 = opq(kv.x * kv.x), p1 = opq(kv.y * kv.y);
                float p2 = opq(kv.z * kv.z), p3 = opq(kv.w * kv.w);
                if (c4 < 2) { r[j] = p0; r[j + 1] = p1; r[j + 2] = p2; r[j + 3] = p3; }
                else        { r[j] += p0; r[j + 1] += p1; r[j + 2] += p2; r[j + 3] += p3; }
            }
            float kn = ((r[0] + r[1]) + (r[2] + r[3])) + ((r[4] + r[5]) + (r[6] + r[7]));
            float t1 = opq(2.0f * acc);
            float t2 = opq(qn - t1);
            float dnp = t2 + kn;
            pk = ((u64)__float_as_uint(dnp) << 32) | nb;
        } else {
            pk = ~0ULL;
        }
        s[i] = pk;
    }
    __syncthreads();

    // bitonic sort 512 u64 ascending => numpy top_k(-d) with lowest-index ties
    for (int k2 = 2; k2 <= CPQ; k2 <<= 1) {
        for (int j = k2 >> 1; j > 0; j >>= 1) {
            #pragma unroll
            for (int m = 0; m < 2; ++m) {
                int i = t + 256 * m;
                int ixj = i ^ j;
                if (ixj > i) {
                    u64 a = s[i], b = s[ixj];
                    bool up = ((i & k2) == 0);
                    if ((a > b) == up) { s[i] = b; s[ixj] = a; }
                }
            }
            __syncthreads();
        }
    }

    // numpy-faithful direct-form rescore of top-50 + weights
    if (t < 64) { sww[t] = 0.0f; svv[t] = 0.0f; }
    __syncthreads();
    if (t < K) {
        unsigned nb = (unsigned)(s[t] & 0xffffffffu);
        const float4* kr = (const float4*)(Ky + (size_t)nb * D);
        const float4* qr = (const float4*)qs;
        float r[8];
        #pragma unroll
        for (int c4 = 0; c4 < 32; ++c4) {
            float4 kv = kr[c4];
            float4 qv = qr[c4];
            float d0 = qv.x - kv.x, d1 = qv.y - kv.y;
            float d2 = qv.z - kv.z, d3 = qv.w - kv.w;
            float p0 = opq(d0 * d0), p1 = opq(d1 * d1);
            float p2 = opq(d2 * d2), p3 = opq(d3 * d3);
            int j = (c4 & 1) * 4;
            if (c4 < 2) { r[j] = p0; r[j + 1] = p1; r[j + 2] = p2; r[j + 3] = p3; }
            else        { r[j] += p0; r[j + 1] += p1; r[j + 2] += p2; r[j + 3] += p3; }
        }
        float sq = ((r[0] + r[1]) + (r[2] + r[3])) + ((r[4] + r[5]) + (r[6] + r[7]));
        sww[t] = 1.0f / (sq + 1e-3f);
        svv[t] = V[nb];
    }
    __syncthreads();
    if (t == 0) {
        float r[8];
        #pragma unroll
        for (int j = 0; j < 8; ++j) r[j] = sww[j];
        for (int i = 8; i < 48; i += 8)
            #pragma unroll
            for (int j = 0; j < 8; ++j) r[j] += sww[i + j];
        float W = ((r[0] + r[1]) + (r[2] + r[3])) + ((r[4] + r[5]) + (r[6] + r[7]));
        W += sww[48];
        W += sww[49];
        float p[50];
        for (int i = 0; i < 50; ++i) {
            float wn = opq(sww[i] / W);
            p[i] = opq(wn * svv[i]);
        }
        #pragma unroll
        for (int j = 0; j < 8; ++j) r[j] = p[j];
        for (int i = 8; i < 48; i += 8)
            #pragma unroll
            for (int j = 0; j < 8; ++j) r[j] += p[i + j];
        float res = ((r[0] + r[1]) + (r[2] + r[3])) + ((r[4] + r[5]) + (r[6] + r[7]));
        res += p[48];
        res += p[49];
        out[q] = res;
    }
}

extern "C" void kernel_launch(void* const* d_in, const int* in_sizes, int n_in,
                              void* d_out, int out_size, void* d_ws, size_t ws_size,
                              hipStream_t stream) {
    const float* Q  = (const float*)d_in[0];
    const float* Ky = (const float*)d_in[1];
    const float* V  = (const float*)d_in[2];
    float* out = (float*)d_out;

    float* kn = (float*)d_ws;                 // 100000 floats
    float* qn = kn + N;                       // 2048 floats
    u64* cand = (u64*)(qn + B);               // 2048*512 u64  (~8.4 MB)

    k_norms<<<dim3((N + B) / 4), 256, 0, stream>>>(Q, Ky, qn, kn);
    k_phase1<<<dim3(NCHUNK, B / BQ), 512, 0, stream>>>(Q, Ky, qn, kn, cand);
    k_phase2<<<dim3(B), 256, 0, stream>>>(Q, Ky, V, cand, out);
}